// Round 9
// baseline (347.944 us; speedup 1.0000x reference)
//
#include <hip/hip_runtime.h>

#define NDIM 8
#define P_PAIRS 28
#define HID 128
#define BATCH_N 65536
#define TILE_M 256
#define THREADS 1024
#define TILES_PER_BLOCK 4

#define LOG2E 1.4426950408889634f
#define LN2   0.6931471805599453f

typedef __attribute__((ext_vector_type(8))) short bf16x8;
typedef __attribute__((ext_vector_type(4))) float f32x4;

// compiler-only fence: forbids reordering LDS stores/loads across it (TBAA guard)
#define MEM_FENCE asm volatile("" ::: "memory")

__device__ __forceinline__ unsigned short f32_to_bf16(float f) {
  union { float f; unsigned u; } v; v.f = f;
  unsigned r = v.u + 0x7FFFu + ((v.u >> 16) & 1u);
  return (unsigned short)(r >> 16);
}

__device__ __forceinline__ unsigned cvt_pk_bf16(float a, float b) {
  unsigned r;
  asm("v_cvt_pk_bf16_f32 %0, %1, %2" : "=v"(r) : "v"(a), "v"(b));
  return r;
}

__device__ __forceinline__ float fast_exp2(float x) {
  float r; asm("v_exp_f32 %0, %1" : "=v"(r) : "v"(x)); return r;
}
__device__ __forceinline__ float fast_log2(float x) {
  float r; asm("v_log_f32 %0, %1" : "=v"(r) : "v"(x)); return r;
}

// h' = log2(1 + 2^t), t = z*log2e. Clamp at 30: exact + NaN launder.
// ROUND-1: removing the clamp -> NaN. LOAD-BEARING.
// ROUND-3: 5-FMA poly form -> +30%. Keep the 2-trans form.
// ROUND-6: post-cvt packed u16 clamp -> absmax 0.5. f32 fminf BEFORE exp is
//   the only verified form. DO NOT TOUCH THIS FUNCTION.
__device__ __forceinline__ float softplus2(float t) {
  t = fminf(t, 30.0f);
  return fast_log2(1.0f + fast_exp2(t));
}

// XOR-swizzled row-major [r][128] bf16; element group c8 = k>>3 (16B granules)
__device__ __forceinline__ int swz(int r, int c8) {
  return r * 128 + (((c8 ^ (r & 15)) & 15) << 3);
}

// Transpose+convert: Wh (2,28,128,128) f32 -> WT bf16, WT[l][p][n][k] = Wh[l][p][k][n]
__global__ void prep_wt(const float* __restrict__ Wh, unsigned short* __restrict__ WT) {
  __shared__ float tile[32][33];
  int t = blockIdx.x;           // 56*16 blocks
  int lp = t >> 4;
  int sub = t & 15;
  int kt = (sub >> 2) * 32, nt = (sub & 3) * 32;
  const float* src = Wh + (size_t)lp * 16384;
  unsigned short* dst = WT + (size_t)lp * 16384;
  int tx = threadIdx.x & 31, ty = threadIdx.x >> 5;   // 32 x 8
#pragma unroll
  for (int r = 0; r < 32; r += 8)
    tile[r + ty][tx] = src[(kt + r + ty) * 128 + (nt + tx)];
  __syncthreads();
#pragma unroll
  for (int r = 0; r < 32; r += 8)
    dst[(nt + r + ty) * 128 + (kt + tx)] = f32_to_bf16(tile[tx][r + ty]);
}

// LESSONS LEDGER (verified on HW):
//  R5: permlane register transpose of h  -> SLOWER (moves work onto saturated
//      VALU; LDS pipe was NOT binding despite 7.34M bank conflicts).
//  R7: layer-3 weights in registers (w1f[4][8]) -> CATASTROPHIC: over the
//      launch_bounds(1024,4) VGPR budget; compiler remats the GLOBAL loads
//      in-loop (FETCH x140). LDS-sourced hoists are safe (remat == re-read).
//  R8: s_sleep temporal skew of SIMD partners -> NULL. The 30% VALU idle is
//      per-wave dependency latency, not cross-wave burst collision.
__launch_bounds__(THREADS, 4)
__global__ void mlp_pairs(const float* __restrict__ x,
                          const float* __restrict__ W1,
                          const float* __restrict__ b1,
                          const float* __restrict__ bh,
                          const float* __restrict__ Wout,
                          const float* __restrict__ bout,
                          const int* __restrict__ rel_idx,
                          const int* __restrict__ i_idx,
                          const int* __restrict__ j_idx,
                          const unsigned short* __restrict__ WT,
                          float* __restrict__ out) {
  const int p = blockIdx.y;
  const int bx = blockIdx.x;          // batch group: rows [bx*1024, bx*1024+1024)
  const int tid = (int)threadIdx.x;
  const int lane = tid & 63;
  const int wave = tid >> 6;          // 0..15, each wave owns 16 rows per tile
  const int qd = lane >> 4;
  const int ln = lane & 15;
  const int mrow = wave * 16;

  __shared__ __align__(16) unsigned short w0_lds[128 * 128];   // 32 KB, swizzled [n][k]
  __shared__ __align__(16) unsigned short w1_lds[128 * 128];   // 32 KB, swizzled [n][k]
  __shared__ __align__(16) unsigned short h_lds[TILE_M * 128]; // 64 KB, swizzled [m][k]
  __shared__ __align__(16) unsigned short w1t_lds[128][8];     //  2 KB
  __shared__ __align__(16) float bh0s[128];
  __shared__ __align__(16) float bh1s[128];
  __shared__ __align__(16) float wouts[128];
  // total ~131.5 KB -> 1 block/CU, 16 waves = 4 waves/SIMD

  // ---- stage both hidden-layer weight slabs, swizzled (ONCE per block) ----
  {
    const uint4* s0 = reinterpret_cast<const uint4*>(WT + (size_t)p * 16384);
    const uint4* s1 = reinterpret_cast<const uint4*>(WT + (size_t)(P_PAIRS + p) * 16384);
#pragma unroll
    for (int it = 0; it < 2; ++it) {
      int idx = it * THREADS + tid;    // 0..2047
      int r = idx >> 4, c = idx & 15;
      uint4 a = s0[idx];
      uint4 b = s1[idx];
      int off = swz(r, c);
      *reinterpret_cast<uint4*>(&w0_lds[off]) = a;
      *reinterpret_cast<uint4*>(&w1_lds[off]) = b;
    }
  }
  const int ii = i_idx[p], jj = j_idx[p];
  if (tid < 128) {
    // W1 zero-padded 6->8 rows, consuming the RAW x row (no runtime gather):
    //   row k = W1 row (k - (k>ii) - (k>jj))   for k not in {ii,jj}
    //   row jj = 0
    //   row ii = b1  (bias folded into K; x slot ii forced to 1.0 -> C=0)
    // All prescaled by log2e.
    int n = tid;
    unsigned short u[8];
#pragma unroll
    for (int k = 0; k < 8; ++k) {
      int d = k - (k > ii) - (k > jj);
      float w;
      if (k == ii)      w = b1[p * 128 + n] * LOG2E;
      else if (k == jj) w = 0.f;
      else              w = W1[(p * 6 + d) * 128 + n] * LOG2E;
      u[k] = f32_to_bf16(w);
    }
    uint4 pk;
    pk.x = (unsigned)u[0] | ((unsigned)u[1] << 16);
    pk.y = (unsigned)u[2] | ((unsigned)u[3] << 16);
    pk.z = (unsigned)u[4] | ((unsigned)u[5] << 16);
    pk.w = (unsigned)u[6] | ((unsigned)u[7] << 16);
    *reinterpret_cast<uint4*>(&w1t_lds[n][0]) = pk;
  } else if (tid < 256) {
    int n = tid - 128;
    bh0s[n] = bh[p * 128 + n] * LOG2E;
    bh1s[n] = bh[(P_PAIRS + p) * 128 + n] * LOG2E;
    wouts[n] = Wout[p * 128 + n] * LN2;
  }
  const float bp = bout[p];

  // masks to force bf16 x-slot ii := 1.0 (0x3F80) in the packed B fragment
  unsigned amsk[4], omsk[4];
  {
    unsigned am = (ii & 1) ? 0x0000FFFFu : 0xFFFF0000u;
    unsigned om = 0x3F80u << ((ii & 1) * 16);
    int wi = ii >> 1;
#pragma unroll
    for (int w = 0; w < 4; ++w) {
      amsk[w] = (w == wi) ? am : 0xFFFFFFFFu;
      omsk[w] = (w == wi) ? om : 0u;
    }
  }
  __syncthreads();   // the ONLY barrier

  // ---- tile order: 4-way phase rotation ----
  const int phase = wave >> 2;

  // ---- precomputed tile-invariant LDS element offsets ----
  // swz(r, 4*ks+qd) = r*128 + ((qd^(ln&3))<<3) + (((ks^(ln>>2))&3)<<5)
  // swz(m, 2*nt+qh)+(qd&1)*4 = hw0 XOR (nt<<4)
  const int ln3 = ln & 3;
  const int rdx = ((qd ^ ln3) << 3) + ((ln >> 2) << 5);
  const int a0  = ln * 128 + rdx;              // weight-frag base (ks=0), + nt*2048 imm
  const int b0  = (mrow + ln) * 128 + rdx;     // h-frag base (ks=0)
  const int hw0 = (mrow + ln) * 128 + (((qd >> 1) ^ (ln & 1)) << 3)
                + (((ln >> 1) & 7) << 4) + (qd & 1) * 4;   // h-write base (nt=0)

  // ---- hoist tile-invariant bh0/bh1 bias fragments into registers ----
  // (16 f32x4 = 64 VGPR; LDS-sourced, so allocator pressure degrades to the
  //  current per-tile LDS read, never a global remat. wouts stays in LDS to
  //  keep total VGPR under the launch_bounds(1024,4) cap of 128.)
  f32x4 bh0r[8], bh1r[8];
#pragma unroll
  for (int nt = 0; nt < 8; ++nt) {
    bh0r[nt] = *reinterpret_cast<const f32x4*>(&bh0s[nt * 16 + qd * 4]);
    bh1r[nt] = *reinterpret_cast<const f32x4*>(&bh1s[nt * 16 + qd * 4]);
  }

  // ---- prefetch first tile's x (lane<16: one 32B row each) ----
  float4 xa = {0.f, 0.f, 0.f, 0.f}, xb = {0.f, 0.f, 0.f, 0.f};
  {
    int row = bx * (TILE_M * TILES_PER_BLOCK) + phase * TILE_M + mrow + ln;
    const float4* xr = reinterpret_cast<const float4*>(x + (size_t)row * 8);
    if (lane < 16) { xa = xr[0]; xb = xr[1]; }
  }

  for (int s = 0; s < TILES_PER_BLOCK; ++s) {
    const int itile = (s + phase) & 3;
    const int row0 = bx * (TILE_M * TILES_PER_BLOCK) + itile * TILE_M;

    // ---- layer-1 B fragment in registers: raw x row, slot ii := 1.0 ----
    bf16x8 zero8 = {};
    bf16x8 bfr1 = zero8;
    if (lane < 16) {
      uint4 pk;
      pk.x = (cvt_pk_bf16(xa.x, xa.y) & amsk[0]) | omsk[0];
      pk.y = (cvt_pk_bf16(xa.z, xa.w) & amsk[1]) | omsk[1];
      pk.z = (cvt_pk_bf16(xb.x, xb.y) & amsk[2]) | omsk[2];
      pk.w = (cvt_pk_bf16(xb.z, xb.w) & amsk[3]) | omsk[3];
      bfr1 = __builtin_bit_cast(bf16x8, pk);
    }
    // ---- prefetch next tile's x (overlaps this tile's compute) ----
    if (s + 1 < TILES_PER_BLOCK && lane < 16) {
      int nrow0 = bx * (TILE_M * TILES_PER_BLOCK) + (((s + 1 + phase) & 3)) * TILE_M;
      const float4* xr = reinterpret_cast<const float4*>(x + (size_t)(nrow0 + mrow + ln) * 8);
      xa = xr[0]; xb = xr[1];
    }

    f32x4 acc[8];

    // ===== Layer 1: single K-step, C = 0 (bias folded into K) =====
    {
      f32x4 zc = {0.f, 0.f, 0.f, 0.f};
#pragma unroll
      for (int nt = 0; nt < 8; ++nt) {
        bf16x8 afr = zero8;
        if (qd == 0)
          afr = *reinterpret_cast<const bf16x8*>(&w1t_lds[nt * 16 + ln][0]);
        acc[nt] = __builtin_amdgcn_mfma_f32_16x16x32_bf16(afr, bfr1, zc, 0, 0, 0);
      }
    }
#pragma unroll
    for (int nt = 0; nt < 8; ++nt) {
      uint2 pk;
      pk.x = cvt_pk_bf16(softplus2(acc[nt][0]), softplus2(acc[nt][1]));
      pk.y = cvt_pk_bf16(softplus2(acc[nt][2]), softplus2(acc[nt][3]));
      *reinterpret_cast<uint2*>(&h_lds[hw0 ^ (nt << 4)]) = pk;
    }
    MEM_FENCE;   // layer-1 h write -> layer-2 fragment read ordering

    // ===== Layer 2: ks=0 peeled (bias as C), ks=1..3 accumulate =====
    {
      bf16x8 bfr = *reinterpret_cast<const bf16x8*>(&h_lds[b0]);
#pragma unroll
      for (int nt = 0; nt < 8; ++nt) {
        bf16x8 afr = *reinterpret_cast<const bf16x8*>(&w0_lds[a0 + nt * 2048]);
        acc[nt] = __builtin_amdgcn_mfma_f32_16x16x32_bf16(afr, bfr, bh0r[nt], 0, 0, 0);
      }
    }
#pragma unroll
    for (int ks = 1; ks < 4; ++ks) {
      bf16x8 bfr = *reinterpret_cast<const bf16x8*>(&h_lds[b0 ^ (ks << 5)]);
      bf16x8 afr[8];
#pragma unroll
      for (int nt = 0; nt < 8; ++nt)
        afr[nt] = *reinterpret_cast<const bf16x8*>(&w0_lds[(a0 ^ (ks << 5)) + nt * 2048]);
#pragma unroll
      for (int nt = 0; nt < 8; ++nt)
        acc[nt] = __builtin_amdgcn_mfma_f32_16x16x32_bf16(afr[nt], bfr, acc[nt], 0, 0, 0);
    }
#pragma unroll
    for (int nt = 0; nt < 8; ++nt) {
      uint2 pk;
      pk.x = cvt_pk_bf16(softplus2(acc[nt][0]), softplus2(acc[nt][1]));
      pk.y = cvt_pk_bf16(softplus2(acc[nt][2]), softplus2(acc[nt][3]));
      *reinterpret_cast<uint2*>(&h_lds[hw0 ^ (nt << 4)]) = pk;
    }
    MEM_FENCE;   // layer-2 h write -> layer-3 fragment read ordering

    // ===== Layer 3: ks=0 peeled (bias as C), then output dot =====
    {
      bf16x8 bfr = *reinterpret_cast<const bf16x8*>(&h_lds[b0]);
#pragma unroll
      for (int nt = 0; nt < 8; ++nt) {
        bf16x8 afr = *reinterpret_cast<const bf16x8*>(&w1_lds[a0 + nt * 2048]);
        acc[nt] = __builtin_amdgcn_mfma_f32_16x16x32_bf16(afr, bfr, bh1r[nt], 0, 0, 0);
      }
    }
#pragma unroll
    for (int ks = 1; ks < 4; ++ks) {
      bf16x8 bfr = *reinterpret_cast<const bf16x8*>(&h_lds[b0 ^ (ks << 5)]);
      bf16x8 afr[8];
#pragma unroll
      for (int nt = 0; nt < 8; ++nt)
        afr[nt] = *reinterpret_cast<const bf16x8*>(&w1_lds[(a0 ^ (ks << 5)) + nt * 2048]);
#pragma unroll
      for (int nt = 0; nt < 8; ++nt)
        acc[nt] = __builtin_amdgcn_mfma_f32_16x16x32_bf16(afr[nt], bfr, acc[nt], 0, 0, 0);
    }
    float pv = 0.f;
#pragma unroll
    for (int nt = 0; nt < 8; ++nt) {
      f32x4 wo4 = *reinterpret_cast<const f32x4*>(&wouts[nt * 16 + qd * 4]);
#pragma unroll
      for (int r = 0; r < 4; ++r)
        pv += wo4[r] * softplus2(acc[nt][r]);
    }

    {
      float v = pv;
      v += __shfl_xor(v, 16, 64);
      v += __shfl_xor(v, 32, 64);
      if (lane < 16) {
        int mg = row0 + mrow + lane;
        float val = v + bp;
        out[mg * 64 + ii * 8 + jj] = val;
        out[mg * 64 + jj * 8 + ii] = -val;
        if (p == 0) {
#pragma unroll
          for (int d = 0; d < 8; ++d)
            out[mg * 64 + d * 9] = 0.f;
        }
      }
    }
    MEM_FENCE;   // tile s h reads done before tile s+1 h overwrite
  }
}

extern "C" void kernel_launch(void* const* d_in, const int* in_sizes, int n_in,
                              void* d_out, int out_size, void* d_ws, size_t ws_size,
                              hipStream_t stream) {
  const float* x    = (const float*)d_in[0];
  const float* W1   = (const float*)d_in[1];
  const float* b1   = (const float*)d_in[2];
  const float* Wh   = (const float*)d_in[3];
  const float* bh   = (const float*)d_in[4];
  const float* Wout = (const float*)d_in[5];
  const float* bout = (const float*)d_in[6];
  const int* rel    = (const int*)d_in[7];
  const int* iidx   = (const int*)d_in[8];
  const int* jidx   = (const int*)d_in[9];
  float* out = (float*)d_out;
  unsigned short* WT = (unsigned short*)d_ws;  // 2*28*128*128 bf16 = 1.84 MB

  prep_wt<<<dim3(56 * 16), 256, 0, stream>>>(Wh, WT);
  dim3 grid(BATCH_N / (TILE_M * TILES_PER_BLOCK), P_PAIRS);   // (64, 28)
  mlp_pairs<<<grid, THREADS, 0, stream>>>(x, W1, b1, bh, Wout, bout, rel, iidx, jidx, WT, out);
}

// Round 10
// 307.169 us; speedup vs baseline: 1.1327x; 1.1327x over previous
//
#include <hip/hip_runtime.h>

#define NDIM 8
#define P_PAIRS 28
#define HID 128
#define BATCH_N 65536
#define TILE_M 256
#define THREADS 1024
#define TILES_PER_BLOCK 4

#define LOG2E 1.4426950408889634f
#define LN2   0.6931471805599453f

typedef __attribute__((ext_vector_type(8))) short bf16x8;
typedef __attribute__((ext_vector_type(4))) float f32x4;

// compiler-only fence: forbids reordering LDS stores/loads across it (TBAA guard)
#define MEM_FENCE asm volatile("" ::: "memory")

__device__ __forceinline__ unsigned short f32_to_bf16(float f) {
  union { float f; unsigned u; } v; v.f = f;
  unsigned r = v.u + 0x7FFFu + ((v.u >> 16) & 1u);
  return (unsigned short)(r >> 16);
}

__device__ __forceinline__ unsigned cvt_pk_bf16(float a, float b) {
  unsigned r;
  asm("v_cvt_pk_bf16_f32 %0, %1, %2" : "=v"(r) : "v"(a), "v"(b));
  return r;
}

__device__ __forceinline__ float fast_exp2(float x) {
  float r; asm("v_exp_f32 %0, %1" : "=v"(r) : "v"(x)); return r;
}
__device__ __forceinline__ float fast_log2(float x) {
  float r; asm("v_log_f32 %0, %1" : "=v"(r) : "v"(x)); return r;
}

// h' = log2(1 + 2^t), t = z*log2e. Clamp at 30: exact + NaN launder.
// ROUND-1: removing the clamp -> NaN. LOAD-BEARING.
// ROUND-3: 5-FMA poly form -> +30%. Keep the 2-trans form.
// ROUND-6: post-cvt packed u16 clamp -> absmax 0.5. f32 fminf BEFORE exp is
//   the only verified form. DO NOT TOUCH THIS FUNCTION.
__device__ __forceinline__ float softplus2(float t) {
  t = fminf(t, 30.0f);
  return fast_log2(1.0f + fast_exp2(t));
}

// XOR-swizzled row-major [r][128] bf16; element group c8 = k>>3 (16B granules)
__device__ __forceinline__ int swz(int r, int c8) {
  return r * 128 + (((c8 ^ (r & 15)) & 15) << 3);
}

// Transpose+convert: Wh (2,28,128,128) f32 -> WT bf16, WT[l][p][n][k] = Wh[l][p][k][n]
__global__ void prep_wt(const float* __restrict__ Wh, unsigned short* __restrict__ WT) {
  __shared__ float tile[32][33];
  int t = blockIdx.x;           // 56*16 blocks
  int lp = t >> 4;
  int sub = t & 15;
  int kt = (sub >> 2) * 32, nt = (sub & 3) * 32;
  const float* src = Wh + (size_t)lp * 16384;
  unsigned short* dst = WT + (size_t)lp * 16384;
  int tx = threadIdx.x & 31, ty = threadIdx.x >> 5;   // 32 x 8
#pragma unroll
  for (int r = 0; r < 32; r += 8)
    tile[r + ty][tx] = src[(kt + r + ty) * 128 + (nt + tx)];
  __syncthreads();
#pragma unroll
  for (int r = 0; r < 32; r += 8)
    dst[(nt + r + ty) * 128 + (kt + tx)] = f32_to_bf16(tile[tx][r + ty]);
}

// LESSONS LEDGER (verified on HW) — this is the ROUND-4 kernel, the best of
// 9 measured variants (271.3 us dispatch). Every structural alternative was
// tried and regressed/nulled:
//  R1: removing softplus clamp -> NaN (clamp launders transient NaN).
//  R3: softplus as minimax poly -> +30% (dependent FMA chain on saturated VALU).
//  R5: permlane register transpose of h -> +7% (moves LDS work onto VALU;
//      7.34M bank conflicts were FREE — LDS pipe not binding).
//  R6: packed u16 post-cvt clamp -> WRONG VALUES (VOP3P semantics hazard).
//  R7: layer-3 weights in 128 VGPRs -> FETCH x140 (global remat in-loop).
//  R8: s_sleep skew of SIMD partners -> null (idle is per-wave dep latency).
//  R9: bh bias frags in 64 VGPRs -> scratch spill (FETCH x9, WRITE x2.7).
// Constraint set: VALU/trans saturated at 4 waves/SIMD; occupancy capped by
// irreducible 128KB LDS working set; register paths capped by spill cliff;
// softplus algebra frozen. Do not re-try ledger items.
__launch_bounds__(THREADS, 4)
__global__ void mlp_pairs(const float* __restrict__ x,
                          const float* __restrict__ W1,
                          const float* __restrict__ b1,
                          const float* __restrict__ bh,
                          const float* __restrict__ Wout,
                          const float* __restrict__ bout,
                          const int* __restrict__ rel_idx,
                          const int* __restrict__ i_idx,
                          const int* __restrict__ j_idx,
                          const unsigned short* __restrict__ WT,
                          float* __restrict__ out) {
  const int p = blockIdx.y;
  const int bx = blockIdx.x;          // batch group: rows [bx*1024, bx*1024+1024)
  const int tid = (int)threadIdx.x;
  const int lane = tid & 63;
  const int wave = tid >> 6;          // 0..15, each wave owns 16 rows per tile
  const int qd = lane >> 4;
  const int ln = lane & 15;
  const int mrow = wave * 16;

  __shared__ __align__(16) unsigned short w0_lds[128 * 128];   // 32 KB, swizzled [n][k]
  __shared__ __align__(16) unsigned short w1_lds[128 * 128];   // 32 KB, swizzled [n][k]
  __shared__ __align__(16) unsigned short h_lds[TILE_M * 128]; // 64 KB, swizzled [m][k]
  __shared__ __align__(16) unsigned short w1t_lds[128][8];     //  2 KB
  __shared__ __align__(16) float bh0s[128];
  __shared__ __align__(16) float bh1s[128];
  __shared__ __align__(16) float wouts[128];
  // total ~131.5 KB -> 1 block/CU, 16 waves = 4 waves/SIMD

  // ---- stage both hidden-layer weight slabs, swizzled (ONCE per block) ----
  {
    const uint4* s0 = reinterpret_cast<const uint4*>(WT + (size_t)p * 16384);
    const uint4* s1 = reinterpret_cast<const uint4*>(WT + (size_t)(P_PAIRS + p) * 16384);
#pragma unroll
    for (int it = 0; it < 2; ++it) {
      int idx = it * THREADS + tid;    // 0..2047
      int r = idx >> 4, c = idx & 15;
      uint4 a = s0[idx];
      uint4 b = s1[idx];
      int off = swz(r, c);
      *reinterpret_cast<uint4*>(&w0_lds[off]) = a;
      *reinterpret_cast<uint4*>(&w1_lds[off]) = b;
    }
  }
  const int ii = i_idx[p], jj = j_idx[p];
  if (tid < 128) {
    // W1 zero-padded 6->8 rows, consuming the RAW x row (no runtime gather):
    //   row k = W1 row (k - (k>ii) - (k>jj))   for k not in {ii,jj}
    //   row jj = 0
    //   row ii = b1  (bias folded into K; x slot ii forced to 1.0 -> C=0)
    // All prescaled by log2e.
    int n = tid;
    unsigned short u[8];
#pragma unroll
    for (int k = 0; k < 8; ++k) {
      int d = k - (k > ii) - (k > jj);
      float w;
      if (k == ii)      w = b1[p * 128 + n] * LOG2E;
      else if (k == jj) w = 0.f;
      else              w = W1[(p * 6 + d) * 128 + n] * LOG2E;
      u[k] = f32_to_bf16(w);
    }
    uint4 pk;
    pk.x = (unsigned)u[0] | ((unsigned)u[1] << 16);
    pk.y = (unsigned)u[2] | ((unsigned)u[3] << 16);
    pk.z = (unsigned)u[4] | ((unsigned)u[5] << 16);
    pk.w = (unsigned)u[6] | ((unsigned)u[7] << 16);
    *reinterpret_cast<uint4*>(&w1t_lds[n][0]) = pk;
  } else if (tid < 256) {
    int n = tid - 128;
    bh0s[n] = bh[p * 128 + n] * LOG2E;
    bh1s[n] = bh[(P_PAIRS + p) * 128 + n] * LOG2E;
    wouts[n] = Wout[p * 128 + n] * LN2;
  }
  const float bp = bout[p];

  // masks to force bf16 x-slot ii := 1.0 (0x3F80) in the packed B fragment
  unsigned amsk[4], omsk[4];
  {
    unsigned am = (ii & 1) ? 0x0000FFFFu : 0xFFFF0000u;
    unsigned om = 0x3F80u << ((ii & 1) * 16);
    int wi = ii >> 1;
#pragma unroll
    for (int w = 0; w < 4; ++w) {
      amsk[w] = (w == wi) ? am : 0xFFFFFFFFu;
      omsk[w] = (w == wi) ? om : 0u;
    }
  }
  __syncthreads();   // the ONLY barrier

  // ---- tile order: 4-way phase rotation ----
  const int phase = wave >> 2;

  // ---- precomputed tile-invariant LDS element offsets ----
  // swz(r, 4*ks+qd) = r*128 + ((qd^(ln&3))<<3) + (((ks^(ln>>2))&3)<<5)
  // swz(m, 2*nt+qh)+(qd&1)*4 = hw0 XOR (nt<<4)
  const int ln3 = ln & 3;
  const int rdx = ((qd ^ ln3) << 3) + ((ln >> 2) << 5);
  const int a0  = ln * 128 + rdx;              // weight-frag base (ks=0), + nt*2048 imm
  const int b0  = (mrow + ln) * 128 + rdx;     // h-frag base (ks=0)
  const int hw0 = (mrow + ln) * 128 + (((qd >> 1) ^ (ln & 1)) << 3)
                + (((ln >> 1) & 7) << 4) + (qd & 1) * 4;   // h-write base (nt=0)

  // ---- hoist tile-invariant Wout into registers ----
  f32x4 wreg[8];
#pragma unroll
  for (int nt = 0; nt < 8; ++nt)
    wreg[nt] = *reinterpret_cast<const f32x4*>(&wouts[nt * 16 + qd * 4]);

  // ---- prefetch first tile's x (lane<16: one 32B row each) ----
  float4 xa = {0.f, 0.f, 0.f, 0.f}, xb = {0.f, 0.f, 0.f, 0.f};
  {
    int row = bx * (TILE_M * TILES_PER_BLOCK) + phase * TILE_M + mrow + ln;
    const float4* xr = reinterpret_cast<const float4*>(x + (size_t)row * 8);
    if (lane < 16) { xa = xr[0]; xb = xr[1]; }
  }

  for (int s = 0; s < TILES_PER_BLOCK; ++s) {
    const int itile = (s + phase) & 3;
    const int row0 = bx * (TILE_M * TILES_PER_BLOCK) + itile * TILE_M;

    // ---- layer-1 B fragment in registers: raw x row, slot ii := 1.0 ----
    bf16x8 zero8 = {};
    bf16x8 bfr1 = zero8;
    if (lane < 16) {
      uint4 pk;
      pk.x = (cvt_pk_bf16(xa.x, xa.y) & amsk[0]) | omsk[0];
      pk.y = (cvt_pk_bf16(xa.z, xa.w) & amsk[1]) | omsk[1];
      pk.z = (cvt_pk_bf16(xb.x, xb.y) & amsk[2]) | omsk[2];
      pk.w = (cvt_pk_bf16(xb.z, xb.w) & amsk[3]) | omsk[3];
      bfr1 = __builtin_bit_cast(bf16x8, pk);
    }
    // ---- prefetch next tile's x (overlaps this tile's compute) ----
    if (s + 1 < TILES_PER_BLOCK && lane < 16) {
      int nrow0 = bx * (TILE_M * TILES_PER_BLOCK) + (((s + 1 + phase) & 3)) * TILE_M;
      const float4* xr = reinterpret_cast<const float4*>(x + (size_t)(nrow0 + mrow + ln) * 8);
      xa = xr[0]; xb = xr[1];
    }

    f32x4 acc[8];

    // ===== Layer 1: single K-step, C = 0 (bias folded into K) =====
    {
      f32x4 zc = {0.f, 0.f, 0.f, 0.f};
#pragma unroll
      for (int nt = 0; nt < 8; ++nt) {
        bf16x8 afr = zero8;
        if (qd == 0)
          afr = *reinterpret_cast<const bf16x8*>(&w1t_lds[nt * 16 + ln][0]);
        acc[nt] = __builtin_amdgcn_mfma_f32_16x16x32_bf16(afr, bfr1, zc, 0, 0, 0);
      }
    }
#pragma unroll
    for (int nt = 0; nt < 8; ++nt) {
      uint2 pk;
      pk.x = cvt_pk_bf16(softplus2(acc[nt][0]), softplus2(acc[nt][1]));
      pk.y = cvt_pk_bf16(softplus2(acc[nt][2]), softplus2(acc[nt][3]));
      *reinterpret_cast<uint2*>(&h_lds[hw0 ^ (nt << 4)]) = pk;
    }
    MEM_FENCE;   // layer-1 h write -> layer-2 fragment read ordering

    // ===== Layer 2: ks=0 peeled (bias as C), ks=1..3 accumulate =====
    {
      bf16x8 bfr = *reinterpret_cast<const bf16x8*>(&h_lds[b0]);
#pragma unroll
      for (int nt = 0; nt < 8; ++nt) {
        bf16x8 afr = *reinterpret_cast<const bf16x8*>(&w0_lds[a0 + nt * 2048]);
        f32x4 b4 = *reinterpret_cast<const f32x4*>(&bh0s[nt * 16 + qd * 4]);
        acc[nt] = __builtin_amdgcn_mfma_f32_16x16x32_bf16(afr, bfr, b4, 0, 0, 0);
      }
    }
#pragma unroll
    for (int ks = 1; ks < 4; ++ks) {
      bf16x8 bfr = *reinterpret_cast<const bf16x8*>(&h_lds[b0 ^ (ks << 5)]);
      bf16x8 afr[8];
#pragma unroll
      for (int nt = 0; nt < 8; ++nt)
        afr[nt] = *reinterpret_cast<const bf16x8*>(&w0_lds[(a0 ^ (ks << 5)) + nt * 2048]);
#pragma unroll
      for (int nt = 0; nt < 8; ++nt)
        acc[nt] = __builtin_amdgcn_mfma_f32_16x16x32_bf16(afr[nt], bfr, acc[nt], 0, 0, 0);
    }
#pragma unroll
    for (int nt = 0; nt < 8; ++nt) {
      uint2 pk;
      pk.x = cvt_pk_bf16(softplus2(acc[nt][0]), softplus2(acc[nt][1]));
      pk.y = cvt_pk_bf16(softplus2(acc[nt][2]), softplus2(acc[nt][3]));
      *reinterpret_cast<uint2*>(&h_lds[hw0 ^ (nt << 4)]) = pk;
    }
    MEM_FENCE;   // layer-2 h write -> layer-3 fragment read ordering

    // ===== Layer 3: ks=0 peeled (bias as C), then output dot =====
    {
      bf16x8 bfr = *reinterpret_cast<const bf16x8*>(&h_lds[b0]);
#pragma unroll
      for (int nt = 0; nt < 8; ++nt) {
        bf16x8 afr = *reinterpret_cast<const bf16x8*>(&w1_lds[a0 + nt * 2048]);
        f32x4 b4 = *reinterpret_cast<const f32x4*>(&bh1s[nt * 16 + qd * 4]);
        acc[nt] = __builtin_amdgcn_mfma_f32_16x16x32_bf16(afr, bfr, b4, 0, 0, 0);
      }
    }
#pragma unroll
    for (int ks = 1; ks < 4; ++ks) {
      bf16x8 bfr = *reinterpret_cast<const bf16x8*>(&h_lds[b0 ^ (ks << 5)]);
      bf16x8 afr[8];
#pragma unroll
      for (int nt = 0; nt < 8; ++nt)
        afr[nt] = *reinterpret_cast<const bf16x8*>(&w1_lds[(a0 ^ (ks << 5)) + nt * 2048]);
#pragma unroll
      for (int nt = 0; nt < 8; ++nt)
        acc[nt] = __builtin_amdgcn_mfma_f32_16x16x32_bf16(afr[nt], bfr, acc[nt], 0, 0, 0);
    }
    float pv = 0.f;
#pragma unroll
    for (int nt = 0; nt < 8; ++nt) {
#pragma unroll
      for (int r = 0; r < 4; ++r)
        pv += wreg[nt][r] * softplus2(acc[nt][r]);
    }

    {
      float v = pv;
      v += __shfl_xor(v, 16, 64);
      v += __shfl_xor(v, 32, 64);
      if (lane < 16) {
        int mg = row0 + mrow + lane;
        float val = v + bp;
        out[mg * 64 + ii * 8 + jj] = val;
        out[mg * 64 + jj * 8 + ii] = -val;
        if (p == 0) {
#pragma unroll
          for (int d = 0; d < 8; ++d)
            out[mg * 64 + d * 9] = 0.f;
        }
      }
    }
    MEM_FENCE;   // tile s h reads done before tile s+1 h overwrite
  }
}

extern "C" void kernel_launch(void* const* d_in, const int* in_sizes, int n_in,
                              void* d_out, int out_size, void* d_ws, size_t ws_size,
                              hipStream_t stream) {
  const float* x    = (const float*)d_in[0];
  const float* W1   = (const float*)d_in[1];
  const float* b1   = (const float*)d_in[2];
  const float* Wh   = (const float*)d_in[3];
  const float* bh   = (const float*)d_in[4];
  const float* Wout = (const float*)d_in[5];
  const float* bout = (const float*)d_in[6];
  const int* rel    = (const int*)d_in[7];
  const int* iidx   = (const int*)d_in[8];
  const int* jidx   = (const int*)d_in[9];
  float* out = (float*)d_out;
  unsigned short* WT = (unsigned short*)d_ws;  // 2*28*128*128 bf16 = 1.84 MB

  prep_wt<<<dim3(56 * 16), 256, 0, stream>>>(Wh, WT);
  dim3 grid(BATCH_N / (TILE_M * TILES_PER_BLOCK), P_PAIRS);   // (64, 28)
  mlp_pairs<<<grid, THREADS, 0, stream>>>(x, W1, b1, bh, Wout, bout, rel, iidx, jidx, WT, out);
}